// Round 1
// baseline (311.483 us; speedup 1.0000x reference)
//
#include <hip/hip_runtime.h>

#define BATCH 2
#define L_SEQ 2048
#define DI 2048
#define NROW (BATCH * L_SEQ)   // 4096
#define E_DIM 96
#define RNK 64                 // DT_RANK
#define NST 16                 // D_STATE
#define NCH 32                 // chunks
#define CL 64                  // chunk length (NCH*CL == L_SEQ)

// ---------------- workspace layout (floats) ----------------
// xdbl : [NROW][96]                          393216
// hloc : [BATCH][NCH][DI][16]               2097152  (becomes hcarry after S2)
// dsum : [BATCH][NCH][DI]                    131072
#define WS_XDBL 0
#define WS_HLOC 393216
#define WS_DSUM (393216 + 2097152)

__device__ __forceinline__ float softplusf(float z) {
    return fmaxf(z, 0.f) + log1pf(__expf(-fabsf(z)));
}

// ============ K1: x_dbl = x @ W_xproj^T  (4096x2048 * 2048x96) ============
// tile 128 rows x 96 cols, k-split 8 (256 k each), atomicAdd epilogue.
__global__ __launch_bounds__(256) void gemm_xproj(const float* __restrict__ x,
                                                  const float* __restrict__ Wx,
                                                  float* __restrict__ xdbl) {
    __shared__ float xs[32][129];   // [k][row], padded
    __shared__ float wsh[32][97];   // [k][e], padded
    const int tid = threadIdx.x;
    const int r0 = blockIdx.x * 128;
    const int kbase0 = blockIdx.y * 256;
    const int rg = tid >> 4;   // 16 groups of 8 rows
    const int cg = tid & 15;   // 16 groups of 6 cols

    float acc[8][6];
#pragma unroll
    for (int i = 0; i < 8; i++)
#pragma unroll
        for (int j = 0; j < 6; j++) acc[i][j] = 0.f;

    for (int kt = 0; kt < 8; kt++) {
        const int kb = kbase0 + kt * 32;
        // load x tile: 128 rows x 32 k (transposed into LDS)
#pragma unroll
        for (int rep = 0; rep < 4; rep++) {
            int i = rep * 256 + tid;       // 0..1023
            int row = i >> 3;              // 0..127
            int kq = i & 7;                // 0..7
            float4 v = *(const float4*)&x[(long)(r0 + row) * DI + kb + kq * 4];
            xs[kq * 4 + 0][row] = v.x;
            xs[kq * 4 + 1][row] = v.y;
            xs[kq * 4 + 2][row] = v.z;
            xs[kq * 4 + 3][row] = v.w;
        }
        // load W tile: 96 e x 32 k
#pragma unroll
        for (int rep = 0; rep < 3; rep++) {
            int i = rep * 256 + tid;       // 0..767
            int e = i >> 3;                // 0..95
            int kq = i & 7;
            float4 v = *(const float4*)&Wx[(long)e * DI + kb + kq * 4];
            wsh[kq * 4 + 0][e] = v.x;
            wsh[kq * 4 + 1][e] = v.y;
            wsh[kq * 4 + 2][e] = v.z;
            wsh[kq * 4 + 3][e] = v.w;
        }
        __syncthreads();
#pragma unroll 8
        for (int k = 0; k < 32; k++) {
            float xr[8], wr[6];
#pragma unroll
            for (int i = 0; i < 8; i++) xr[i] = xs[k][rg * 8 + i];
#pragma unroll
            for (int j = 0; j < 6; j++) wr[j] = wsh[k][cg * 6 + j];
#pragma unroll
            for (int i = 0; i < 8; i++)
#pragma unroll
                for (int j = 0; j < 6; j++) acc[i][j] = fmaf(xr[i], wr[j], acc[i][j]);
        }
        __syncthreads();
    }
#pragma unroll
    for (int i = 0; i < 8; i++) {
        int row = r0 + rg * 8 + i;
#pragma unroll
        for (int j = 0; j < 6; j++)
            atomicAdd(&xdbl[(long)row * E_DIM + cg * 6 + j], acc[i][j]);
    }
}

// ============ K2: delta = softplus(dlt @ W_dt^T + b_dt) -> d_out ============
// tile 64 rows x 64 d, K=64 single pass.
__global__ __launch_bounds__(256) void gemm_dt(const float* __restrict__ xdbl,
                                               const float* __restrict__ Wdt,
                                               const float* __restrict__ b_dt,
                                               float* __restrict__ delta) {
    __shared__ float dl[64][65];   // [k][row]
    __shared__ float wt[64][65];   // [k][dd]
    const int tid = threadIdx.x;
    const int row0 = blockIdx.x * 64;
    const int d0 = blockIdx.y * 64;

#pragma unroll
    for (int rep = 0; rep < 4; rep++) {
        int i = rep * 256 + tid;    // 0..1023
        int row = i >> 4;           // 0..63
        int kq = i & 15;            // 0..15
        float4 v = *(const float4*)&xdbl[(long)(row0 + row) * E_DIM + kq * 4];
        dl[kq * 4 + 0][row] = v.x;
        dl[kq * 4 + 1][row] = v.y;
        dl[kq * 4 + 2][row] = v.z;
        dl[kq * 4 + 3][row] = v.w;
    }
#pragma unroll
    for (int rep = 0; rep < 4; rep++) {
        int i = rep * 256 + tid;
        int dd = i >> 4;
        int kq = i & 15;
        float4 v = *(const float4*)&Wdt[(long)(d0 + dd) * RNK + kq * 4];
        wt[kq * 4 + 0][dd] = v.x;
        wt[kq * 4 + 1][dd] = v.y;
        wt[kq * 4 + 2][dd] = v.z;
        wt[kq * 4 + 3][dd] = v.w;
    }
    __syncthreads();

    const int rg = tid >> 4;    // 16 groups of 4 rows
    const int cgd = tid & 15;   // 16 groups of 4 d
    float acc[4][4];
#pragma unroll
    for (int i = 0; i < 4; i++)
#pragma unroll
        for (int j = 0; j < 4; j++) acc[i][j] = 0.f;

#pragma unroll 8
    for (int k = 0; k < 64; k++) {
        float xr[4], wr[4];
#pragma unroll
        for (int i = 0; i < 4; i++) xr[i] = dl[k][rg * 4 + i];
#pragma unroll
        for (int j = 0; j < 4; j++) wr[j] = wt[k][cgd * 4 + j];
#pragma unroll
        for (int i = 0; i < 4; i++)
#pragma unroll
            for (int j = 0; j < 4; j++) acc[i][j] = fmaf(xr[i], wr[j], acc[i][j]);
    }

    float4 bb = *(const float4*)&b_dt[d0 + cgd * 4];
#pragma unroll
    for (int i = 0; i < 4; i++) {
        int row = row0 + rg * 4 + i;
        float4 o;
        o.x = softplusf(acc[i][0] + bb.x);
        o.y = softplusf(acc[i][1] + bb.y);
        o.z = softplusf(acc[i][2] + bb.z);
        o.w = softplusf(acc[i][3] + bb.w);
        *(float4*)&delta[(long)row * DI + d0 + cgd * 4] = o;
    }
}

// ============ S1: chunk-local carries (h_final per chunk, h0=0) ============
__global__ __launch_bounds__(256) void scan_carry(const float* __restrict__ x,
                                                  const float* __restrict__ delta,
                                                  const float* __restrict__ xdbl,
                                                  const float* __restrict__ A_log,
                                                  float* __restrict__ hloc,
                                                  float* __restrict__ dsumb) {
    __shared__ float bm[CL * NST];
    const int tid = threadIdx.x;
    const int d = blockIdx.x * 256 + tid;
    const int c = blockIdx.y;
    const int b = blockIdx.z;
    const int row0 = b * L_SEQ + c * CL;

    for (int i = tid; i < CL * NST; i += 256) {
        int ll = i >> 4, n = i & 15;
        bm[i] = xdbl[(long)(row0 + ll) * E_DIM + 64 + n];
    }
    __syncthreads();

    float A[16];
#pragma unroll
    for (int q = 0; q < 4; q++) {
        float4 v = *(const float4*)&A_log[(long)d * NST + q * 4];
        A[q * 4 + 0] = -__expf(v.x);
        A[q * 4 + 1] = -__expf(v.y);
        A[q * 4 + 2] = -__expf(v.z);
        A[q * 4 + 3] = -__expf(v.w);
    }
    float h[16];
#pragma unroll
    for (int n = 0; n < 16; n++) h[n] = 0.f;
    float dsum = 0.f;

    long idx = (long)row0 * DI + d;
    float dn = delta[idx], xn = x[idx];
    for (int ll = 0; ll < CL; ll++) {
        float dc = dn, xc = xn;
        long nidx = (ll + 1 < CL) ? idx + DI : idx;
        dn = delta[nidx];
        xn = x[nidx];
        float du = dc * xc;
        float bl[16];
#pragma unroll
        for (int q = 0; q < 4; q++) {
            float4 v = *(const float4*)&bm[ll * NST + q * 4];
            bl[q * 4 + 0] = v.x; bl[q * 4 + 1] = v.y; bl[q * 4 + 2] = v.z; bl[q * 4 + 3] = v.w;
        }
#pragma unroll
        for (int n = 0; n < 16; n++)
            h[n] = fmaf(__expf(dc * A[n]), h[n], du * bl[n]);
        dsum += dc;
        idx += DI;
    }

    const long cb = ((long)(b * NCH + c) * DI + d);
#pragma unroll
    for (int q = 0; q < 4; q++)
        *(float4*)&hloc[cb * 16 + q * 4] =
            make_float4(h[q * 4], h[q * 4 + 1], h[q * 4 + 2], h[q * 4 + 3]);
    dsumb[cb] = dsum;
}

// ============ S2: prefix over chunks; hloc becomes h_carry (chunk-entry state) ============
__global__ __launch_bounds__(256) void scan_prefix(const float* __restrict__ A_log,
                                                   float* __restrict__ hloc,
                                                   const float* __restrict__ dsumb) {
    const int g = blockIdx.x * 256 + threadIdx.x;   // 65536 threads
    const int n = g & 15;
    const int d = (g >> 4) & (DI - 1);
    const int b = g >> 15;
    const float An = -__expf(A_log[(long)d * NST + n]);
    float hc = 0.f;
    for (int c = 0; c < NCH; c++) {
        const long cb = ((long)(b * NCH + c) * DI + d);
        float hl = hloc[cb * 16 + n];
        float dsv = dsumb[cb];
        hloc[cb * 16 + n] = hc;               // overwrite with carry (entry state)
        hc = fmaf(__expf(An * dsv), hc, hl);  // true state at end of chunk c
    }
}

// ============ S3: output pass — full scan per chunk from true h_init ============
__global__ __launch_bounds__(256) void scan_out(const float* __restrict__ x,
                                                const float* __restrict__ xdbl,
                                                const float* __restrict__ A_log,
                                                const float* __restrict__ Dp,
                                                const float* __restrict__ hloc,
                                                float* out) {
    __shared__ float bm[CL * NST];
    __shared__ float cm[CL * NST];
    const int tid = threadIdx.x;
    const int d = blockIdx.x * 256 + tid;
    const int c = blockIdx.y;
    const int b = blockIdx.z;
    const int row0 = b * L_SEQ + c * CL;

    for (int i = tid; i < CL * NST; i += 256) {
        int ll = i >> 4, n = i & 15;
        bm[i] = xdbl[(long)(row0 + ll) * E_DIM + 64 + n];
        cm[i] = xdbl[(long)(row0 + ll) * E_DIM + 80 + n];
    }
    __syncthreads();

    float A[16];
#pragma unroll
    for (int q = 0; q < 4; q++) {
        float4 v = *(const float4*)&A_log[(long)d * NST + q * 4];
        A[q * 4 + 0] = -__expf(v.x);
        A[q * 4 + 1] = -__expf(v.y);
        A[q * 4 + 2] = -__expf(v.z);
        A[q * 4 + 3] = -__expf(v.w);
    }
    float h[16];
    const long cb = ((long)(b * NCH + c) * DI + d);
#pragma unroll
    for (int q = 0; q < 4; q++) {
        float4 v = *(const float4*)&hloc[cb * 16 + q * 4];
        h[q * 4 + 0] = v.x; h[q * 4 + 1] = v.y; h[q * 4 + 2] = v.z; h[q * 4 + 3] = v.w;
    }
    const float Dd = Dp[d];

    long idx = (long)row0 * DI + d;
    float dn = out[idx], xn = x[idx];   // out currently holds delta
    for (int ll = 0; ll < CL; ll++) {
        float dc = dn, xc = xn;
        long nidx = (ll + 1 < CL) ? idx + DI : idx;
        dn = out[nidx];
        xn = x[nidx];
        float du = dc * xc;
        float bl[16], clv[16];
#pragma unroll
        for (int q = 0; q < 4; q++) {
            float4 v = *(const float4*)&bm[ll * NST + q * 4];
            bl[q * 4 + 0] = v.x; bl[q * 4 + 1] = v.y; bl[q * 4 + 2] = v.z; bl[q * 4 + 3] = v.w;
            float4 w = *(const float4*)&cm[ll * NST + q * 4];
            clv[q * 4 + 0] = w.x; clv[q * 4 + 1] = w.y; clv[q * 4 + 2] = w.z; clv[q * 4 + 3] = w.w;
        }
        float y = 0.f;
#pragma unroll
        for (int n = 0; n < 16; n++) {
            h[n] = fmaf(__expf(dc * A[n]), h[n], du * bl[n]);
            y = fmaf(h[n], clv[n], y);
        }
        out[idx] = fmaf(xc, Dd, y);
        idx += DI;
    }
}

extern "C" void kernel_launch(void* const* d_in, const int* in_sizes, int n_in,
                              void* d_out, int out_size, void* d_ws, size_t ws_size,
                              hipStream_t stream) {
    const float* x    = (const float*)d_in[0];
    const float* Wx   = (const float*)d_in[1];
    const float* Wdt  = (const float*)d_in[2];
    const float* bdt  = (const float*)d_in[3];
    const float* Alog = (const float*)d_in[4];
    const float* Dp   = (const float*)d_in[5];
    float* out = (float*)d_out;
    float* ws = (float*)d_ws;
    float* xdbl  = ws + WS_XDBL;
    float* hloc  = ws + WS_HLOC;
    float* dsumb = ws + WS_DSUM;

    hipMemsetAsync(xdbl, 0, (size_t)NROW * E_DIM * sizeof(float), stream);
    gemm_xproj<<<dim3(NROW / 128, 8), 256, 0, stream>>>(x, Wx, xdbl);
    gemm_dt<<<dim3(NROW / 64, DI / 64), 256, 0, stream>>>(xdbl, Wdt, bdt, out);
    scan_carry<<<dim3(DI / 256, NCH, BATCH), 256, 0, stream>>>(x, out, xdbl, Alog, hloc, dsumb);
    scan_prefix<<<dim3(BATCH * DI * NST / 256), 256, 0, stream>>>(Alog, hloc, dsumb);
    scan_out<<<dim3(DI / 256, NCH, BATCH), 256, 0, stream>>>(x, xdbl, Alog, Dp, hloc, out);
}

// Round 2
// 229.532 us; speedup vs baseline: 1.3570x; 1.3570x over previous
//
#include <hip/hip_runtime.h>

#define BATCH 2
#define L_SEQ 2048
#define DI 2048
#define NROW (BATCH * L_SEQ)   // 4096
#define E_DIM 96
#define RNK 64                 // DT_RANK
#define NST 16                 // D_STATE
#define NCH 64                 // chunks
#define CL 32                  // chunk length (NCH*CL == L_SEQ)
#define SPLITK 16              // K1 split-K factor
#define KSL (DI / SPLITK)      // 128 k per split

// ---------------- workspace layout (floats) ----------------
// xdbl  : [NROW][96]                              393216
// region2 (overlaid, disjoint lifetimes):
//   partials : [SPLITK][NROW][96]   6291456  (K1 -> reduce, then dead)
//   hloc     : [BATCH][NCH][DI][16] 4194304  (S1 -> S3)
//   dsum     : [BATCH][NCH][DI]      262144
#define WS_XDBL 0
#define WS_PART 393216
#define WS_HLOC 393216
#define WS_DSUM (393216 + 4194304)

__device__ __forceinline__ float softplusf(float z) {
    return fmaxf(z, 0.f) + log1pf(__expf(-fabsf(z)));
}

// ===== K1a: partial[s] = x[:, s*128:(s+1)*128] @ W^T slice  =====
// block: 128 threads, tile M=64 x N=96, k-step 32, 4 steps. grid (64, 16).
__global__ __launch_bounds__(128) void gemm_xproj_part(const float* __restrict__ x,
                                                       const float* __restrict__ Wx,
                                                       float* __restrict__ part) {
    __shared__ float xs[32][65];    // [k][row]
    __shared__ float wsh[32][97];   // [k][e]
    const int tid = threadIdx.x;
    const int r0 = blockIdx.x * 64;
    const int kbase0 = blockIdx.y * KSL;
    const int rg = tid >> 4;   // 8 groups of 8 rows
    const int cg = tid & 15;   // 16 groups of 6 cols

    float acc[8][6];
#pragma unroll
    for (int i = 0; i < 8; i++)
#pragma unroll
        for (int j = 0; j < 6; j++) acc[i][j] = 0.f;

    for (int kt = 0; kt < KSL / 32; kt++) {
        const int kb = kbase0 + kt * 32;
        // x tile: 64 rows x 32 k -> transposed LDS. 512 float4, 4/thread.
#pragma unroll
        for (int rep = 0; rep < 4; rep++) {
            int i = rep * 128 + tid;   // 0..511
            int row = i >> 3;          // 0..63
            int kq = i & 7;
            float4 v = *(const float4*)&x[(long)(r0 + row) * DI + kb + kq * 4];
            xs[kq * 4 + 0][row] = v.x;
            xs[kq * 4 + 1][row] = v.y;
            xs[kq * 4 + 2][row] = v.z;
            xs[kq * 4 + 3][row] = v.w;
        }
        // W tile: 96 e x 32 k. 768 float4, 6/thread.
#pragma unroll
        for (int rep = 0; rep < 6; rep++) {
            int i = rep * 128 + tid;   // 0..767
            int e = i >> 3;            // 0..95
            int kq = i & 7;
            float4 v = *(const float4*)&Wx[(long)e * DI + kb + kq * 4];
            wsh[kq * 4 + 0][e] = v.x;
            wsh[kq * 4 + 1][e] = v.y;
            wsh[kq * 4 + 2][e] = v.z;
            wsh[kq * 4 + 3][e] = v.w;
        }
        __syncthreads();
#pragma unroll 4
        for (int k = 0; k < 32; k++) {
            float xr[8], wr[6];
#pragma unroll
            for (int i = 0; i < 8; i++) xr[i] = xs[k][rg * 8 + i];
#pragma unroll
            for (int j = 0; j < 6; j++) wr[j] = wsh[k][cg * 6 + j];
#pragma unroll
            for (int i = 0; i < 8; i++)
#pragma unroll
                for (int j = 0; j < 6; j++) acc[i][j] = fmaf(xr[i], wr[j], acc[i][j]);
        }
        __syncthreads();
    }
    const long sbase = (long)blockIdx.y * NROW * E_DIM;
#pragma unroll
    for (int i = 0; i < 8; i++) {
        long rowb = sbase + (long)(r0 + rg * 8 + i) * E_DIM + cg * 6;
#pragma unroll
        for (int j = 0; j < 6; j++) part[rowb + j] = acc[i][j];
    }
}

// ===== K1b: xdbl = sum over splits (float4-vectorized) =====
__global__ __launch_bounds__(256) void xproj_reduce(const float* __restrict__ part,
                                                    float* __restrict__ xdbl) {
    const int i4 = blockIdx.x * 256 + threadIdx.x;   // 98304 float4 outputs
    const float4* p4 = (const float4*)part;
    float4 s = p4[i4];
#pragma unroll
    for (int sp = 1; sp < SPLITK; sp++) {
        float4 v = p4[(long)sp * (NROW * E_DIM / 4) + i4];
        s.x += v.x; s.y += v.y; s.z += v.z; s.w += v.w;
    }
    ((float4*)xdbl)[i4] = s;
}

// ===== K2: delta = softplus(dlt @ W_dt^T + b_dt) -> d_out =====
// tile 128 rows x 128 d, K=64 in two 32-steps. grid (32, 16).
__global__ __launch_bounds__(256) void gemm_dt(const float* __restrict__ xdbl,
                                               const float* __restrict__ Wdt,
                                               const float* __restrict__ b_dt,
                                               float* __restrict__ delta) {
    __shared__ float dl[32][129];   // [k][row]
    __shared__ float wt[32][129];   // [k][dd]
    const int tid = threadIdx.x;
    const int row0 = blockIdx.x * 128;
    const int d0 = blockIdx.y * 128;
    const int rg = tid >> 4;    // 16 groups of 8 rows
    const int cg = tid & 15;    // 16 groups of 8 d

    float acc[8][8];
#pragma unroll
    for (int i = 0; i < 8; i++)
#pragma unroll
        for (int j = 0; j < 8; j++) acc[i][j] = 0.f;

    for (int kt = 0; kt < 2; kt++) {
        const int kb = kt * 32;
#pragma unroll
        for (int rep = 0; rep < 4; rep++) {
            int i = rep * 256 + tid;    // 0..1023
            int row = i >> 3;           // 0..127
            int kq = i & 7;
            float4 v = *(const float4*)&xdbl[(long)(row0 + row) * E_DIM + kb + kq * 4];
            dl[kq * 4 + 0][row] = v.x;
            dl[kq * 4 + 1][row] = v.y;
            dl[kq * 4 + 2][row] = v.z;
            dl[kq * 4 + 3][row] = v.w;
        }
#pragma unroll
        for (int rep = 0; rep < 4; rep++) {
            int i = rep * 256 + tid;
            int dd = i >> 3;
            int kq = i & 7;
            float4 v = *(const float4*)&Wdt[(long)(d0 + dd) * RNK + kb + kq * 4];
            wt[kq * 4 + 0][dd] = v.x;
            wt[kq * 4 + 1][dd] = v.y;
            wt[kq * 4 + 2][dd] = v.z;
            wt[kq * 4 + 3][dd] = v.w;
        }
        __syncthreads();
#pragma unroll 4
        for (int k = 0; k < 32; k++) {
            float xr[8], wr[8];
#pragma unroll
            for (int i = 0; i < 8; i++) xr[i] = dl[k][rg * 8 + i];
#pragma unroll
            for (int j = 0; j < 8; j++) wr[j] = wt[k][cg * 8 + j];
#pragma unroll
            for (int i = 0; i < 8; i++)
#pragma unroll
                for (int j = 0; j < 8; j++) acc[i][j] = fmaf(xr[i], wr[j], acc[i][j]);
        }
        __syncthreads();
    }

    float4 b0 = *(const float4*)&b_dt[d0 + cg * 8];
    float4 b1 = *(const float4*)&b_dt[d0 + cg * 8 + 4];
#pragma unroll
    for (int i = 0; i < 8; i++) {
        int row = row0 + rg * 8 + i;
        float4 o0, o1;
        o0.x = softplusf(acc[i][0] + b0.x);
        o0.y = softplusf(acc[i][1] + b0.y);
        o0.z = softplusf(acc[i][2] + b0.z);
        o0.w = softplusf(acc[i][3] + b0.w);
        o1.x = softplusf(acc[i][4] + b1.x);
        o1.y = softplusf(acc[i][5] + b1.y);
        o1.z = softplusf(acc[i][6] + b1.z);
        o1.w = softplusf(acc[i][7] + b1.w);
        *(float4*)&delta[(long)row * DI + d0 + cg * 8] = o0;
        *(float4*)&delta[(long)row * DI + d0 + cg * 8 + 4] = o1;
    }
}

// ===== S1: chunk-local carries (h_final per chunk, h0=0) =====
__global__ __launch_bounds__(256) void scan_carry(const float* __restrict__ x,
                                                  const float* __restrict__ delta,
                                                  const float* __restrict__ xdbl,
                                                  const float* __restrict__ A_log,
                                                  float* __restrict__ hloc,
                                                  float* __restrict__ dsumb) {
    __shared__ float bm[CL * NST];
    const int tid = threadIdx.x;
    const int d = blockIdx.x * 256 + tid;
    const int c = blockIdx.y;
    const int b = blockIdx.z;
    const int row0 = b * L_SEQ + c * CL;

    for (int i = tid; i < CL * NST; i += 256) {
        int ll = i >> 4, n = i & 15;
        bm[i] = xdbl[(long)(row0 + ll) * E_DIM + 64 + n];
    }
    __syncthreads();

    float A[16];
#pragma unroll
    for (int q = 0; q < 4; q++) {
        float4 v = *(const float4*)&A_log[(long)d * NST + q * 4];
        A[q * 4 + 0] = -__expf(v.x);
        A[q * 4 + 1] = -__expf(v.y);
        A[q * 4 + 2] = -__expf(v.z);
        A[q * 4 + 3] = -__expf(v.w);
    }
    float h[16];
#pragma unroll
    for (int n = 0; n < 16; n++) h[n] = 0.f;
    float dsum = 0.f;

    long idx = (long)row0 * DI + d;
    float dn = delta[idx], xn = x[idx];
    for (int ll = 0; ll < CL; ll++) {
        float dc = dn, xc = xn;
        long nidx = (ll + 1 < CL) ? idx + DI : idx;
        dn = delta[nidx];
        xn = x[nidx];
        float du = dc * xc;
        float bl[16];
#pragma unroll
        for (int q = 0; q < 4; q++) {
            float4 v = *(const float4*)&bm[ll * NST + q * 4];
            bl[q * 4 + 0] = v.x; bl[q * 4 + 1] = v.y; bl[q * 4 + 2] = v.z; bl[q * 4 + 3] = v.w;
        }
#pragma unroll
        for (int n = 0; n < 16; n++)
            h[n] = fmaf(__expf(dc * A[n]), h[n], du * bl[n]);
        dsum += dc;
        idx += DI;
    }

    const long cb = ((long)(b * NCH + c) * DI + d);
#pragma unroll
    for (int q = 0; q < 4; q++)
        *(float4*)&hloc[cb * 16 + q * 4] =
            make_float4(h[q * 4], h[q * 4 + 1], h[q * 4 + 2], h[q * 4 + 3]);
    dsumb[cb] = dsum;
}

// ===== S2: prefix over chunks; hloc becomes chunk-entry state =====
__global__ __launch_bounds__(256) void scan_prefix(const float* __restrict__ A_log,
                                                   float* __restrict__ hloc,
                                                   const float* __restrict__ dsumb) {
    const int g = blockIdx.x * 256 + threadIdx.x;   // 65536 threads
    const int n = g & 15;
    const int d = (g >> 4) & (DI - 1);
    const int b = g >> 15;
    const float An = -__expf(A_log[(long)d * NST + n]);
    float hc = 0.f;
    for (int c = 0; c < NCH; c++) {
        const long cb = ((long)(b * NCH + c) * DI + d);
        float hl = hloc[cb * 16 + n];
        float dsv = dsumb[cb];
        hloc[cb * 16 + n] = hc;               // overwrite with entry state
        hc = fmaf(__expf(An * dsv), hc, hl);  // state at end of chunk c
    }
}

// ===== S3: output pass — full scan per chunk from true h_init =====
__global__ __launch_bounds__(256) void scan_out(const float* __restrict__ x,
                                                const float* __restrict__ xdbl,
                                                const float* __restrict__ A_log,
                                                const float* __restrict__ Dp,
                                                const float* __restrict__ hloc,
                                                float* out) {
    __shared__ float bm[CL * NST];
    __shared__ float cm[CL * NST];
    const int tid = threadIdx.x;
    const int d = blockIdx.x * 256 + tid;
    const int c = blockIdx.y;
    const int b = blockIdx.z;
    const int row0 = b * L_SEQ + c * CL;

    for (int i = tid; i < CL * NST; i += 256) {
        int ll = i >> 4, n = i & 15;
        bm[i] = xdbl[(long)(row0 + ll) * E_DIM + 64 + n];
        cm[i] = xdbl[(long)(row0 + ll) * E_DIM + 80 + n];
    }
    __syncthreads();

    float A[16];
#pragma unroll
    for (int q = 0; q < 4; q++) {
        float4 v = *(const float4*)&A_log[(long)d * NST + q * 4];
        A[q * 4 + 0] = -__expf(v.x);
        A[q * 4 + 1] = -__expf(v.y);
        A[q * 4 + 2] = -__expf(v.z);
        A[q * 4 + 3] = -__expf(v.w);
    }
    float h[16];
    const long cb = ((long)(b * NCH + c) * DI + d);
#pragma unroll
    for (int q = 0; q < 4; q++) {
        float4 v = *(const float4*)&hloc[cb * 16 + q * 4];
        h[q * 4 + 0] = v.x; h[q * 4 + 1] = v.y; h[q * 4 + 2] = v.z; h[q * 4 + 3] = v.w;
    }
    const float Dd = Dp[d];

    long idx = (long)row0 * DI + d;
    float dn = out[idx], xn = x[idx];   // out currently holds delta
    for (int ll = 0; ll < CL; ll++) {
        float dc = dn, xc = xn;
        long nidx = (ll + 1 < CL) ? idx + DI : idx;
        dn = out[nidx];
        xn = x[nidx];
        float du = dc * xc;
        float bl[16], clv[16];
#pragma unroll
        for (int q = 0; q < 4; q++) {
            float4 v = *(const float4*)&bm[ll * NST + q * 4];
            bl[q * 4 + 0] = v.x; bl[q * 4 + 1] = v.y; bl[q * 4 + 2] = v.z; bl[q * 4 + 3] = v.w;
            float4 w = *(const float4*)&cm[ll * NST + q * 4];
            clv[q * 4 + 0] = w.x; clv[q * 4 + 1] = w.y; clv[q * 4 + 2] = w.z; clv[q * 4 + 3] = w.w;
        }
        float y = 0.f;
#pragma unroll
        for (int n = 0; n < 16; n++) {
            h[n] = fmaf(__expf(dc * A[n]), h[n], du * bl[n]);
            y = fmaf(h[n], clv[n], y);
        }
        out[idx] = fmaf(xc, Dd, y);
        idx += DI;
    }
}

extern "C" void kernel_launch(void* const* d_in, const int* in_sizes, int n_in,
                              void* d_out, int out_size, void* d_ws, size_t ws_size,
                              hipStream_t stream) {
    const float* x    = (const float*)d_in[0];
    const float* Wx   = (const float*)d_in[1];
    const float* Wdt  = (const float*)d_in[2];
    const float* bdt  = (const float*)d_in[3];
    const float* Alog = (const float*)d_in[4];
    const float* Dp   = (const float*)d_in[5];
    float* out = (float*)d_out;
    float* ws = (float*)d_ws;
    float* xdbl  = ws + WS_XDBL;
    float* partb = ws + WS_PART;
    float* hloc  = ws + WS_HLOC;   // overlays partb (disjoint lifetime)
    float* dsumb = ws + WS_DSUM;

    gemm_xproj_part<<<dim3(NROW / 64, SPLITK), 128, 0, stream>>>(x, Wx, partb);
    xproj_reduce<<<dim3(NROW * E_DIM / 4 / 256), 256, 0, stream>>>(partb, xdbl);
    gemm_dt<<<dim3(NROW / 128, DI / 128), 256, 0, stream>>>(xdbl, Wdt, bdt, out);
    scan_carry<<<dim3(DI / 256, NCH, BATCH), 256, 0, stream>>>(x, out, xdbl, Alog, hloc, dsumb);
    scan_prefix<<<dim3(BATCH * DI * NST / 256), 256, 0, stream>>>(Alog, hloc, dsumb);
    scan_out<<<dim3(DI / 256, NCH, BATCH), 256, 0, stream>>>(x, xdbl, Alog, Dp, hloc, out);
}

// Round 3
// 223.284 us; speedup vs baseline: 1.3950x; 1.0280x over previous
//
#include <hip/hip_runtime.h>

#define BATCH 2
#define L_SEQ 2048
#define DI 2048
#define NROW (BATCH * L_SEQ)   // 4096
#define E_DIM 96
#define RNK 64                 // DT_RANK
#define NST 16                 // D_STATE
#define NCH 64                 // chunks
#define CL 32                  // chunk length (NCH*CL == L_SEQ)
#define SPLITK 16              // K1 split-K factor
#define KSL (DI / SPLITK)      // 128 k per split

// ---------------- workspace layout (floats) ----------------
// xdbl  : [NROW][96]                              393216
// region2 (overlaid, disjoint lifetimes):
//   partials : [SPLITK][NROW][96]   6291456  (K1 -> reduce, then dead)
//   hloc     : [BATCH][NCH][DI][16] 4194304  (S1 -> S3)
//   dsum     : [BATCH][NCH][DI]      262144
#define WS_XDBL 0
#define WS_PART 393216
#define WS_HLOC 393216
#define WS_DSUM (393216 + 4194304)

__device__ __forceinline__ float softplusf(float z) {
    return fmaxf(z, 0.f) + log1pf(__expf(-fabsf(z)));
}

// ===== K1a: partial[s] = x[:, ksl] @ W^T slice =====
// 256 threads, tile M=64 x N=96, k-step 32, KSL=128. grid (64, 16).
// LDS pitches 68/100 floats: 16B-aligned rows -> ds_read_b128 works.
__global__ __launch_bounds__(256) void gemm_xproj_part(const float* __restrict__ x,
                                                       const float* __restrict__ Wx,
                                                       float* __restrict__ part) {
    __shared__ float xs[32][68];    // [k][row], pitch 272B (16B aligned)
    __shared__ float wsh[32][100];  // [k][e],  pitch 400B (16B aligned)
    const int tid = threadIdx.x;
    const int r0 = blockIdx.x * 64;
    const int kbase0 = blockIdx.y * KSL;
    const int rg = tid >> 4;   // 16 groups of 4 rows
    const int cg = tid & 15;   // 16 groups of 6 cols

    float acc[4][6];
#pragma unroll
    for (int i = 0; i < 4; i++)
#pragma unroll
        for (int j = 0; j < 6; j++) acc[i][j] = 0.f;

    for (int kt = 0; kt < KSL / 32; kt++) {
        const int kb = kbase0 + kt * 32;
        // x tile: 64 rows x 32 k -> transposed LDS. 512 float4, 2/thread.
#pragma unroll
        for (int rep = 0; rep < 2; rep++) {
            int i = rep * 256 + tid;   // 0..511
            int row = i >> 3;          // 0..63
            int kq = i & 7;
            float4 v = *(const float4*)&x[(long)(r0 + row) * DI + kb + kq * 4];
            xs[kq * 4 + 0][row] = v.x;
            xs[kq * 4 + 1][row] = v.y;
            xs[kq * 4 + 2][row] = v.z;
            xs[kq * 4 + 3][row] = v.w;
        }
        // W tile: 96 e x 32 k. 768 float4, 3/thread.
#pragma unroll
        for (int rep = 0; rep < 3; rep++) {
            int i = rep * 256 + tid;   // 0..767
            int e = i >> 3;            // 0..95
            int kq = i & 7;
            float4 v = *(const float4*)&Wx[(long)e * DI + kb + kq * 4];
            wsh[kq * 4 + 0][e] = v.x;
            wsh[kq * 4 + 1][e] = v.y;
            wsh[kq * 4 + 2][e] = v.z;
            wsh[kq * 4 + 3][e] = v.w;
        }
        __syncthreads();
#pragma unroll 8
        for (int k = 0; k < 32; k++) {
            float xr[4], wr[6];
#pragma unroll
            for (int i = 0; i < 4; i++) xr[i] = xs[k][rg * 4 + i];   // 1x ds_read_b128
#pragma unroll
            for (int j = 0; j < 6; j++) wr[j] = wsh[k][cg * 6 + j];  // 3x ds_read_b64
#pragma unroll
            for (int i = 0; i < 4; i++)
#pragma unroll
                for (int j = 0; j < 6; j++) acc[i][j] = fmaf(xr[i], wr[j], acc[i][j]);
        }
        __syncthreads();
    }
    const long sbase = (long)blockIdx.y * NROW * E_DIM;
#pragma unroll
    for (int i = 0; i < 4; i++) {
        long rowb = sbase + (long)(r0 + rg * 4 + i) * E_DIM + cg * 6;
#pragma unroll
        for (int j = 0; j < 6; j++) part[rowb + j] = acc[i][j];
    }
}

// ===== K1b: xdbl = sum over splits (float4-vectorized) =====
__global__ __launch_bounds__(256) void xproj_reduce(const float* __restrict__ part,
                                                    float* __restrict__ xdbl) {
    const int i4 = blockIdx.x * 256 + threadIdx.x;   // 98304 float4 outputs
    const float4* p4 = (const float4*)part;
    float4 s = p4[i4];
#pragma unroll
    for (int sp = 1; sp < SPLITK; sp++) {
        float4 v = p4[(long)sp * (NROW * E_DIM / 4) + i4];
        s.x += v.x; s.y += v.y; s.z += v.z; s.w += v.w;
    }
    ((float4*)xdbl)[i4] = s;
}

// ===== S1 (fused dt-GEMM): delta = softplus(dlt . Wdt[d] + b_dt[d]) computed
// inline; chunk-local h carries + dsum; delta written to d_out for S3. =====
__global__ __launch_bounds__(256) void scan_carry_fused(const float* __restrict__ x,
                                                        const float* __restrict__ xdbl,
                                                        const float* __restrict__ Wdt,
                                                        const float* __restrict__ bdt,
                                                        const float* __restrict__ A_log,
                                                        float* __restrict__ delta_out,
                                                        float* __restrict__ hloc,
                                                        float* __restrict__ dsumb) {
    __shared__ float dlt_s[CL][RNK];   // 32 x 64, broadcast-read
    __shared__ float bm[CL * NST];     // 32 x 16
    const int tid = threadIdx.x;
    const int d = blockIdx.x * 256 + tid;
    const int c = blockIdx.y;
    const int b = blockIdx.z;
    const int row0 = b * L_SEQ + c * CL;

    // stage xdbl[row][0:80] : 32 rows x 20 float4 = 640 float4
    for (int j = tid; j < CL * 20; j += 256) {
        int row = j / 20, q = j % 20;
        float4 v = *(const float4*)&xdbl[(long)(row0 + row) * E_DIM + q * 4];
        if (q < 16) {
            *(float4*)&dlt_s[row][q * 4] = v;
        } else {
            int n = (q - 16) * 4;
            bm[row * NST + n + 0] = v.x;
            bm[row * NST + n + 1] = v.y;
            bm[row * NST + n + 2] = v.z;
            bm[row * NST + n + 3] = v.w;
        }
    }
    __syncthreads();

    // Wdt row for this d -> 64 VGPRs
    float wdtr[64];
#pragma unroll
    for (int q = 0; q < 16; q++) {
        float4 v = *(const float4*)&Wdt[(long)d * RNK + q * 4];
        wdtr[q * 4 + 0] = v.x; wdtr[q * 4 + 1] = v.y;
        wdtr[q * 4 + 2] = v.z; wdtr[q * 4 + 3] = v.w;
    }
    const float bd = bdt[d];

    float A[16];
#pragma unroll
    for (int q = 0; q < 4; q++) {
        float4 v = *(const float4*)&A_log[(long)d * NST + q * 4];
        A[q * 4 + 0] = -__expf(v.x);
        A[q * 4 + 1] = -__expf(v.y);
        A[q * 4 + 2] = -__expf(v.z);
        A[q * 4 + 3] = -__expf(v.w);
    }
    float h[16];
#pragma unroll
    for (int n = 0; n < 16; n++) h[n] = 0.f;
    float dsum = 0.f;

    long idx = (long)row0 * DI + d;
    float xn = x[idx];
    for (int ll = 0; ll < CL; ll++) {
        float xc = xn;
        if (ll + 1 < CL) xn = x[idx + DI];
        // delta = softplus(dot(dlt_row, wdt_row) + b)
        float dv = bd;
#pragma unroll
        for (int q = 0; q < 16; q++) {
            float4 s = *(const float4*)&dlt_s[ll][q * 4];   // uniform -> broadcast
            dv = fmaf(s.x, wdtr[q * 4 + 0], dv);
            dv = fmaf(s.y, wdtr[q * 4 + 1], dv);
            dv = fmaf(s.z, wdtr[q * 4 + 2], dv);
            dv = fmaf(s.w, wdtr[q * 4 + 3], dv);
        }
        float dc = softplusf(dv);
        delta_out[idx] = dc;               // for S3
        float du = dc * xc;
        float bl[16];
#pragma unroll
        for (int q = 0; q < 4; q++) {
            float4 v = *(const float4*)&bm[ll * NST + q * 4];
            bl[q * 4 + 0] = v.x; bl[q * 4 + 1] = v.y; bl[q * 4 + 2] = v.z; bl[q * 4 + 3] = v.w;
        }
#pragma unroll
        for (int n = 0; n < 16; n++)
            h[n] = fmaf(__expf(dc * A[n]), h[n], du * bl[n]);
        dsum += dc;
        idx += DI;
    }

    const long cb = ((long)(b * NCH + c) * DI + d);
#pragma unroll
    for (int q = 0; q < 4; q++)
        *(float4*)&hloc[cb * 16 + q * 4] =
            make_float4(h[q * 4], h[q * 4 + 1], h[q * 4 + 2], h[q * 4 + 3]);
    dsumb[cb] = dsum;
}

// ===== S2: prefix over chunks; hloc becomes chunk-entry state =====
__global__ __launch_bounds__(256) void scan_prefix(const float* __restrict__ A_log,
                                                   float* __restrict__ hloc,
                                                   const float* __restrict__ dsumb) {
    const int g = blockIdx.x * 256 + threadIdx.x;   // 65536 threads
    const int n = g & 15;
    const int d = (g >> 4) & (DI - 1);
    const int b = g >> 15;
    const float An = -__expf(A_log[(long)d * NST + n]);
    float hc = 0.f;
    for (int c = 0; c < NCH; c++) {
        const long cb = ((long)(b * NCH + c) * DI + d);
        float hl = hloc[cb * 16 + n];
        float dsv = dsumb[cb];
        hloc[cb * 16 + n] = hc;               // overwrite with entry state
        hc = fmaf(__expf(An * dsv), hc, hl);  // state at end of chunk c
    }
}

// ===== S3: output pass — full scan per chunk from true h_init =====
__global__ __launch_bounds__(256) void scan_out(const float* __restrict__ x,
                                                const float* __restrict__ xdbl,
                                                const float* __restrict__ A_log,
                                                const float* __restrict__ Dp,
                                                const float* __restrict__ hloc,
                                                float* out) {
    __shared__ float bm[CL * NST];
    __shared__ float cm[CL * NST];
    const int tid = threadIdx.x;
    const int d = blockIdx.x * 256 + tid;
    const int c = blockIdx.y;
    const int b = blockIdx.z;
    const int row0 = b * L_SEQ + c * CL;

    for (int i = tid; i < CL * NST; i += 256) {
        int ll = i >> 4, n = i & 15;
        bm[i] = xdbl[(long)(row0 + ll) * E_DIM + 64 + n];
        cm[i] = xdbl[(long)(row0 + ll) * E_DIM + 80 + n];
    }
    __syncthreads();

    float A[16];
#pragma unroll
    for (int q = 0; q < 4; q++) {
        float4 v = *(const float4*)&A_log[(long)d * NST + q * 4];
        A[q * 4 + 0] = -__expf(v.x);
        A[q * 4 + 1] = -__expf(v.y);
        A[q * 4 + 2] = -__expf(v.z);
        A[q * 4 + 3] = -__expf(v.w);
    }
    float h[16];
    const long cb = ((long)(b * NCH + c) * DI + d);
#pragma unroll
    for (int q = 0; q < 4; q++) {
        float4 v = *(const float4*)&hloc[cb * 16 + q * 4];
        h[q * 4 + 0] = v.x; h[q * 4 + 1] = v.y; h[q * 4 + 2] = v.z; h[q * 4 + 3] = v.w;
    }
    const float Dd = Dp[d];

    long idx = (long)row0 * DI + d;
    float dn = out[idx], xn = x[idx];   // out currently holds delta
    for (int ll = 0; ll < CL; ll++) {
        float dc = dn, xc = xn;
        long nidx = (ll + 1 < CL) ? idx + DI : idx;
        dn = out[nidx];
        xn = x[nidx];
        float du = dc * xc;
        float bl[16], clv[16];
#pragma unroll
        for (int q = 0; q < 4; q++) {
            float4 v = *(const float4*)&bm[ll * NST + q * 4];
            bl[q * 4 + 0] = v.x; bl[q * 4 + 1] = v.y; bl[q * 4 + 2] = v.z; bl[q * 4 + 3] = v.w;
            float4 w = *(const float4*)&cm[ll * NST + q * 4];
            clv[q * 4 + 0] = w.x; clv[q * 4 + 1] = w.y; clv[q * 4 + 2] = w.z; clv[q * 4 + 3] = w.w;
        }
        float y = 0.f;
#pragma unroll
        for (int n = 0; n < 16; n++) {
            h[n] = fmaf(__expf(dc * A[n]), h[n], du * bl[n]);
            y = fmaf(h[n], clv[n], y);
        }
        out[idx] = fmaf(xc, Dd, y);
        idx += DI;
    }
}

extern "C" void kernel_launch(void* const* d_in, const int* in_sizes, int n_in,
                              void* d_out, int out_size, void* d_ws, size_t ws_size,
                              hipStream_t stream) {
    const float* x    = (const float*)d_in[0];
    const float* Wx   = (const float*)d_in[1];
    const float* Wdt  = (const float*)d_in[2];
    const float* bdt  = (const float*)d_in[3];
    const float* Alog = (const float*)d_in[4];
    const float* Dp   = (const float*)d_in[5];
    float* out = (float*)d_out;
    float* ws = (float*)d_ws;
    float* xdbl  = ws + WS_XDBL;
    float* partb = ws + WS_PART;
    float* hloc  = ws + WS_HLOC;   // overlays partb (disjoint lifetime)
    float* dsumb = ws + WS_DSUM;

    gemm_xproj_part<<<dim3(NROW / 64, SPLITK), 256, 0, stream>>>(x, Wx, partb);
    xproj_reduce<<<dim3(NROW * E_DIM / 4 / 256), 256, 0, stream>>>(partb, xdbl);
    scan_carry_fused<<<dim3(DI / 256, NCH, BATCH), 256, 0, stream>>>(x, xdbl, Wdt, bdt,
                                                                     Alog, out, hloc, dsumb);
    scan_prefix<<<dim3(BATCH * DI * NST / 256), 256, 0, stream>>>(Alog, hloc, dsumb);
    scan_out<<<dim3(DI / 256, NCH, BATCH), 256, 0, stream>>>(x, xdbl, Alog, Dp, hloc, out);
}

// Round 4
// 216.372 us; speedup vs baseline: 1.4396x; 1.0319x over previous
//
#include <hip/hip_runtime.h>

#define BATCH 2
#define L_SEQ 2048
#define DI 2048
#define NROW (BATCH * L_SEQ)   // 4096
#define E_DIM 96
#define RNK 64                 // DT_RANK
#define NST 16                 // D_STATE
#define NCH 64                 // chunks
#define CL 32                  // chunk length (NCH*CL == L_SEQ)
#define SPLITK 16              // K1 split-K factor
#define KSL (DI / SPLITK)      // 128 k per split

// ---------------- workspace layout (floats) ----------------
// xdbl  : [NROW][96]                              393216
// region2 (overlaid, disjoint lifetimes):
//   partials : [SPLITK][NROW][96]   6291456  (K1 -> reduce, then dead)
//   hloc     : [BATCH][NCH][DI][16] 4194304  (S1 -> S3)
//   dsum     : [BATCH][NCH][DI]      262144  (overlaps partials tail; S1 after K1b)
#define WS_XDBL 0
#define WS_PART 393216
#define WS_HLOC 393216
#define WS_DSUM (393216 + 4194304)

__device__ __forceinline__ float softplusf(float z) {
    // max(z,0) + log(1+exp(-|z|)); fast-intrinsic version (err << 0.29 threshold)
    return fmaxf(z, 0.f) + __logf(1.f + __expf(-fabsf(z)));
}

// ===== K1a: partial[s] = x[:, ksl] @ W^T slice =====
// 256 threads, tile M=64 x N=96, k-step 32, KSL=128. grid (64, 16).
__global__ __launch_bounds__(256) void gemm_xproj_part(const float* __restrict__ x,
                                                       const float* __restrict__ Wx,
                                                       float* __restrict__ part) {
    __shared__ float xs[32][68];    // [k][row], pitch 272B (16B aligned)
    __shared__ float wsh[32][100];  // [k][e],  pitch 400B (16B aligned)
    const int tid = threadIdx.x;
    const int r0 = blockIdx.x * 64;
    const int kbase0 = blockIdx.y * KSL;
    const int rg = tid >> 4;   // 16 groups of 4 rows
    const int cg = tid & 15;   // 16 groups of 6 cols

    float acc[4][6];
#pragma unroll
    for (int i = 0; i < 4; i++)
#pragma unroll
        for (int j = 0; j < 6; j++) acc[i][j] = 0.f;

    for (int kt = 0; kt < KSL / 32; kt++) {
        const int kb = kbase0 + kt * 32;
#pragma unroll
        for (int rep = 0; rep < 2; rep++) {
            int i = rep * 256 + tid;   // 0..511
            int row = i >> 3;          // 0..63
            int kq = i & 7;
            float4 v = *(const float4*)&x[(long)(r0 + row) * DI + kb + kq * 4];
            xs[kq * 4 + 0][row] = v.x;
            xs[kq * 4 + 1][row] = v.y;
            xs[kq * 4 + 2][row] = v.z;
            xs[kq * 4 + 3][row] = v.w;
        }
#pragma unroll
        for (int rep = 0; rep < 3; rep++) {
            int i = rep * 256 + tid;   // 0..767
            int e = i >> 3;            // 0..95
            int kq = i & 7;
            float4 v = *(const float4*)&Wx[(long)e * DI + kb + kq * 4];
            wsh[kq * 4 + 0][e] = v.x;
            wsh[kq * 4 + 1][e] = v.y;
            wsh[kq * 4 + 2][e] = v.z;
            wsh[kq * 4 + 3][e] = v.w;
        }
        __syncthreads();
#pragma unroll 8
        for (int k = 0; k < 32; k++) {
            float xr[4], wr[6];
#pragma unroll
            for (int i = 0; i < 4; i++) xr[i] = xs[k][rg * 4 + i];
#pragma unroll
            for (int j = 0; j < 6; j++) wr[j] = wsh[k][cg * 6 + j];
#pragma unroll
            for (int i = 0; i < 4; i++)
#pragma unroll
                for (int j = 0; j < 6; j++) acc[i][j] = fmaf(xr[i], wr[j], acc[i][j]);
        }
        __syncthreads();
    }
    const long sbase = (long)blockIdx.y * NROW * E_DIM;
#pragma unroll
    for (int i = 0; i < 4; i++) {
        long rowb = sbase + (long)(r0 + rg * 4 + i) * E_DIM + cg * 6;
#pragma unroll
        for (int j = 0; j < 6; j++) part[rowb + j] = acc[i][j];
    }
}

// ===== K1b: xdbl = sum over splits (float4-vectorized) =====
__global__ __launch_bounds__(256) void xproj_reduce(const float* __restrict__ part,
                                                    float* __restrict__ xdbl) {
    const int i4 = blockIdx.x * 256 + threadIdx.x;   // 98304 float4 outputs
    const float4* p4 = (const float4*)part;
    float4 s = p4[i4];
#pragma unroll
    for (int sp = 1; sp < SPLITK; sp++) {
        float4 v = p4[(long)sp * (NROW * E_DIM / 4) + i4];
        s.x += v.x; s.y += v.y; s.z += v.z; s.w += v.w;
    }
    ((float4*)xdbl)[i4] = s;
}

// ===== S1 (fused dt-GEMM, LDS-free): per-row operands (dlt, B) are
// block-uniform -> scalar loads (s_load). Wdt[d] in VGPRs (per-thread d).
// delta written to d_out for S3; chunk-local h carries + dsum to ws. =====
__global__ __launch_bounds__(256) void scan_carry_fused(const float* __restrict__ x,
                                                        const float* __restrict__ xdbl,
                                                        const float* __restrict__ Wdt,
                                                        const float* __restrict__ bdt,
                                                        const float* __restrict__ A_log,
                                                        float* __restrict__ delta_out,
                                                        float* __restrict__ hloc,
                                                        float* __restrict__ dsumb) {
    const int tid = threadIdx.x;
    const int d = blockIdx.x * 256 + tid;
    const int c = blockIdx.y;
    const int b = blockIdx.z;
    const int row0 = b * L_SEQ + c * CL;

    float wdtr[64];
#pragma unroll
    for (int q = 0; q < 16; q++) {
        float4 v = *(const float4*)&Wdt[(long)d * RNK + q * 4];
        wdtr[q * 4 + 0] = v.x; wdtr[q * 4 + 1] = v.y;
        wdtr[q * 4 + 2] = v.z; wdtr[q * 4 + 3] = v.w;
    }
    const float bd = bdt[d];

    float A[16];
#pragma unroll
    for (int q = 0; q < 4; q++) {
        float4 v = *(const float4*)&A_log[(long)d * NST + q * 4];
        A[q * 4 + 0] = -__expf(v.x);
        A[q * 4 + 1] = -__expf(v.y);
        A[q * 4 + 2] = -__expf(v.z);
        A[q * 4 + 3] = -__expf(v.w);
    }
    float h[16];
#pragma unroll
    for (int n = 0; n < 16; n++) h[n] = 0.f;
    float dsum = 0.f;

    long idx = (long)row0 * DI + d;
    float xn = x[idx];
    const float* __restrict__ rp = xdbl + (long)row0 * E_DIM;   // uniform row ptr
    for (int ll = 0; ll < CL; ll++) {
        float xc = xn;
        if (ll + 1 < CL) xn = x[idx + DI];
        // dot(dlt_row, Wdt[d]) with 4 accumulators; rp[] uniform -> SGPR operand
        float dv0 = 0.f, dv1 = 0.f, dv2 = 0.f, dv3 = 0.f;
#pragma unroll
        for (int q = 0; q < 16; q++) {
            dv0 = fmaf(rp[q * 4 + 0], wdtr[q * 4 + 0], dv0);
            dv1 = fmaf(rp[q * 4 + 1], wdtr[q * 4 + 1], dv1);
            dv2 = fmaf(rp[q * 4 + 2], wdtr[q * 4 + 2], dv2);
            dv3 = fmaf(rp[q * 4 + 3], wdtr[q * 4 + 3], dv3);
        }
        float dc = softplusf(((dv0 + dv1) + (dv2 + dv3)) + bd);
        delta_out[idx] = dc;               // for S3
        float du = dc * xc;
#pragma unroll
        for (int n = 0; n < 16; n++)
            h[n] = fmaf(__expf(dc * A[n]), h[n], du * rp[64 + n]);   // B: uniform
        dsum += dc;
        idx += DI;
        rp += E_DIM;
    }

    const long cb = ((long)(b * NCH + c) * DI + d);
#pragma unroll
    for (int q = 0; q < 4; q++)
        *(float4*)&hloc[cb * 16 + q * 4] =
            make_float4(h[q * 4], h[q * 4 + 1], h[q * 4 + 2], h[q * 4 + 3]);
    dsumb[cb] = dsum;
}

// ===== S2: prefix over chunks; hloc becomes chunk-entry state =====
__global__ __launch_bounds__(256) void scan_prefix(const float* __restrict__ A_log,
                                                   float* __restrict__ hloc,
                                                   const float* __restrict__ dsumb) {
    const int g = blockIdx.x * 256 + threadIdx.x;   // 65536 threads
    const int n = g & 15;
    const int d = (g >> 4) & (DI - 1);
    const int b = g >> 15;
    const float An = -__expf(A_log[(long)d * NST + n]);
    float hc = 0.f;
    for (int c = 0; c < NCH; c++) {
        const long cb = ((long)(b * NCH + c) * DI + d);
        float hl = hloc[cb * 16 + n];
        float dsv = dsumb[cb];
        hloc[cb * 16 + n] = hc;               // overwrite with entry state
        hc = fmaf(__expf(An * dsv), hc, hl);  // state at end of chunk c
    }
}

// ===== S3 (LDS-free): output pass — full scan per chunk from true h_init.
// B/C rows are block-uniform -> scalar loads. =====
__global__ __launch_bounds__(256) void scan_out(const float* __restrict__ x,
                                                const float* __restrict__ xdbl,
                                                const float* __restrict__ A_log,
                                                const float* __restrict__ Dp,
                                                const float* __restrict__ hloc,
                                                float* __restrict__ out) {
    const int tid = threadIdx.x;
    const int d = blockIdx.x * 256 + tid;
    const int c = blockIdx.y;
    const int b = blockIdx.z;
    const int row0 = b * L_SEQ + c * CL;

    float A[16];
#pragma unroll
    for (int q = 0; q < 4; q++) {
        float4 v = *(const float4*)&A_log[(long)d * NST + q * 4];
        A[q * 4 + 0] = -__expf(v.x);
        A[q * 4 + 1] = -__expf(v.y);
        A[q * 4 + 2] = -__expf(v.z);
        A[q * 4 + 3] = -__expf(v.w);
    }
    float h[16];
    const long cb = ((long)(b * NCH + c) * DI + d);
#pragma unroll
    for (int q = 0; q < 4; q++) {
        float4 v = *(const float4*)&hloc[cb * 16 + q * 4];
        h[q * 4 + 0] = v.x; h[q * 4 + 1] = v.y; h[q * 4 + 2] = v.z; h[q * 4 + 3] = v.w;
    }
    const float Dd = Dp[d];

    long idx = (long)row0 * DI + d;
    float dn = out[idx], xn = x[idx];   // out currently holds delta
    const float* __restrict__ rp = xdbl + (long)row0 * E_DIM;   // uniform row ptr
    for (int ll = 0; ll < CL; ll++) {
        float dc = dn, xc = xn;
        long nidx = (ll + 1 < CL) ? idx + DI : idx;
        dn = out[nidx];
        xn = x[nidx];
        float du = dc * xc;
        float y = 0.f;
#pragma unroll
        for (int n = 0; n < 16; n++) {
            h[n] = fmaf(__expf(dc * A[n]), h[n], du * rp[64 + n]);  // B: uniform
            y = fmaf(h[n], rp[80 + n], y);                          // C: uniform
        }
        out[idx] = fmaf(xc, Dd, y);
        idx += DI;
        rp += E_DIM;
    }
}

extern "C" void kernel_launch(void* const* d_in, const int* in_sizes, int n_in,
                              void* d_out, int out_size, void* d_ws, size_t ws_size,
                              hipStream_t stream) {
    const float* x    = (const float*)d_in[0];
    const float* Wx   = (const float*)d_in[1];
    const float* Wdt  = (const float*)d_in[2];
    const float* bdt  = (const float*)d_in[3];
    const float* Alog = (const float*)d_in[4];
    const float* Dp   = (const float*)d_in[5];
    float* out = (float*)d_out;
    float* ws = (float*)d_ws;
    float* xdbl  = ws + WS_XDBL;
    float* partb = ws + WS_PART;
    float* hloc  = ws + WS_HLOC;   // overlays partb (disjoint lifetime)
    float* dsumb = ws + WS_DSUM;

    gemm_xproj_part<<<dim3(NROW / 64, SPLITK), 256, 0, stream>>>(x, Wx, partb);
    xproj_reduce<<<dim3(NROW * E_DIM / 4 / 256), 256, 0, stream>>>(partb, xdbl);
    scan_carry_fused<<<dim3(DI / 256, NCH, BATCH), 256, 0, stream>>>(x, xdbl, Wdt, bdt,
                                                                     Alog, out, hloc, dsumb);
    scan_prefix<<<dim3(BATCH * DI * NST / 256), 256, 0, stream>>>(Alog, hloc, dsumb);
    scan_out<<<dim3(DI / 256, NCH, BATCH), 256, 0, stream>>>(x, xdbl, Alog, Dp, hloc, out);
}

// Round 5
// 201.472 us; speedup vs baseline: 1.5460x; 1.0740x over previous
//
#include <hip/hip_runtime.h>

#define BATCH 2
#define L_SEQ 2048
#define DI 2048
#define NROW (BATCH * L_SEQ)   // 4096
#define E_DIM 96
#define RNK 64                 // DT_RANK
#define NST 16                 // D_STATE
#define NCH 64                 // chunks
#define CL 32                  // chunk length (NCH*CL == L_SEQ)
#define SPLITK 16              // K1 split-K factor
#define KSL (DI / SPLITK)      // 128 k per split

// ---------------- workspace layout (floats) ----------------
// xdbl  : [NROW][96]                              393216
// region2 (overlaid, disjoint lifetimes):
//   partials : [SPLITK][NROW][96]   6291456  (K1 -> reduce, then dead)
//   hloc     : [BATCH][NCH][DI][16] 4194304  (S1 -> S3)
//   dsum     : [BATCH][NCH][DI]      262144
#define WS_XDBL 0
#define WS_PART 393216
#define WS_HLOC 393216
#define WS_DSUM (393216 + 4194304)

__device__ __forceinline__ float softplusf(float z) {
    return fmaxf(z, 0.f) + __logf(1.f + __expf(-fabsf(z)));
}

// ===== K1a: partial[s] = x[:, ksl] @ W^T slice =====
// 256 threads, tile M=64 x N=96, k-step 32, KSL=128. grid (64, 16).
__global__ __launch_bounds__(256) void gemm_xproj_part(const float* __restrict__ x,
                                                       const float* __restrict__ Wx,
                                                       float* __restrict__ part) {
    __shared__ float xs[32][68];    // [k][row], pitch 272B (16B aligned)
    __shared__ float wsh[32][100];  // [k][e],  pitch 400B (16B aligned)
    const int tid = threadIdx.x;
    const int r0 = blockIdx.x * 64;
    const int kbase0 = blockIdx.y * KSL;
    const int rg = tid >> 4;   // 16 groups of 4 rows
    const int cg = tid & 15;   // 16 groups of 6 cols

    float acc[4][6];
#pragma unroll
    for (int i = 0; i < 4; i++)
#pragma unroll
        for (int j = 0; j < 6; j++) acc[i][j] = 0.f;

    for (int kt = 0; kt < KSL / 32; kt++) {
        const int kb = kbase0 + kt * 32;
#pragma unroll
        for (int rep = 0; rep < 2; rep++) {
            int i = rep * 256 + tid;   // 0..511
            int row = i >> 3;          // 0..63
            int kq = i & 7;
            float4 v = *(const float4*)&x[(long)(r0 + row) * DI + kb + kq * 4];
            xs[kq * 4 + 0][row] = v.x;
            xs[kq * 4 + 1][row] = v.y;
            xs[kq * 4 + 2][row] = v.z;
            xs[kq * 4 + 3][row] = v.w;
        }
#pragma unroll
        for (int rep = 0; rep < 3; rep++) {
            int i = rep * 256 + tid;   // 0..767
            int e = i >> 3;            // 0..95
            int kq = i & 7;
            float4 v = *(const float4*)&Wx[(long)e * DI + kb + kq * 4];
            wsh[kq * 4 + 0][e] = v.x;
            wsh[kq * 4 + 1][e] = v.y;
            wsh[kq * 4 + 2][e] = v.z;
            wsh[kq * 4 + 3][e] = v.w;
        }
        __syncthreads();
#pragma unroll 8
        for (int k = 0; k < 32; k++) {
            float xr[4], wr[6];
#pragma unroll
            for (int i = 0; i < 4; i++) xr[i] = xs[k][rg * 4 + i];
#pragma unroll
            for (int j = 0; j < 6; j++) wr[j] = wsh[k][cg * 6 + j];
#pragma unroll
            for (int i = 0; i < 4; i++)
#pragma unroll
                for (int j = 0; j < 6; j++) acc[i][j] = fmaf(xr[i], wr[j], acc[i][j]);
        }
        __syncthreads();
    }
    const long sbase = (long)blockIdx.y * NROW * E_DIM;
#pragma unroll
    for (int i = 0; i < 4; i++) {
        long rowb = sbase + (long)(r0 + rg * 4 + i) * E_DIM + cg * 6;
#pragma unroll
        for (int j = 0; j < 6; j++) part[rowb + j] = acc[i][j];
    }
}

// ===== K1b: xdbl = sum over splits (float4-vectorized) =====
__global__ __launch_bounds__(256) void xproj_reduce(const float* __restrict__ part,
                                                    float* __restrict__ xdbl) {
    const int i4 = blockIdx.x * 256 + threadIdx.x;   // 98304 float4 outputs
    const float4* p4 = (const float4*)part;
    float4 s = p4[i4];
#pragma unroll
    for (int sp = 1; sp < SPLITK; sp++) {
        float4 v = p4[(long)sp * (NROW * E_DIM / 4) + i4];
        s.x += v.x; s.y += v.y; s.z += v.z; s.w += v.w;
    }
    ((float4*)xdbl)[i4] = s;
}

// ===== K2: delta = softplus(dlt @ Wdt^T + b) -> d_out =====
// tile 64 rows x 128 d, K=64 in two 32-steps. grid (64, 16) = 1024 blocks.
// Conflict-free LDS: pitches 68/132 floats (16B-aligned rows); column read
// uses 16B lane stride (1x ds_read_b128, ~2-way = free); row read broadcast.
__global__ __launch_bounds__(256) void gemm_dt(const float* __restrict__ xdbl,
                                               const float* __restrict__ Wdt,
                                               const float* __restrict__ b_dt,
                                               float* __restrict__ delta) {
    __shared__ float dl[32][68];    // [k][row], pitch 272B
    __shared__ float wt[32][132];   // [k][col], pitch 528B
    const int tid = threadIdx.x;
    const int row0 = blockIdx.x * 64;
    const int d0 = blockIdx.y * 128;
    const int rg = tid >> 5;    // 8 groups of 8 rows
    const int cg = tid & 31;    // 32 groups of 4 cols

    float acc[8][4];
#pragma unroll
    for (int i = 0; i < 8; i++)
#pragma unroll
        for (int j = 0; j < 4; j++) acc[i][j] = 0.f;

    for (int kt = 0; kt < 2; kt++) {
        const int kb = kt * 32;
        // dlt tile: 64 rows x 32 k. 512 float4, 2/thread.
#pragma unroll
        for (int rep = 0; rep < 2; rep++) {
            int i = rep * 256 + tid;
            int row = i >> 3;          // 0..63
            int kq = i & 7;
            float4 v = *(const float4*)&xdbl[(long)(row0 + row) * E_DIM + kb + kq * 4];
            dl[kq * 4 + 0][row] = v.x;
            dl[kq * 4 + 1][row] = v.y;
            dl[kq * 4 + 2][row] = v.z;
            dl[kq * 4 + 3][row] = v.w;
        }
        // Wdt tile: 128 cols x 32 k. 1024 float4, 4/thread.
#pragma unroll
        for (int rep = 0; rep < 4; rep++) {
            int i = rep * 256 + tid;
            int col = i >> 3;          // 0..127
            int kq = i & 7;
            float4 v = *(const float4*)&Wdt[(long)(d0 + col) * RNK + kb + kq * 4];
            wt[kq * 4 + 0][col] = v.x;
            wt[kq * 4 + 1][col] = v.y;
            wt[kq * 4 + 2][col] = v.z;
            wt[kq * 4 + 3][col] = v.w;
        }
        __syncthreads();
#pragma unroll 8
        for (int k = 0; k < 32; k++) {
            float xr[8], wr[4];
#pragma unroll
            for (int i = 0; i < 8; i++) xr[i] = dl[k][rg * 8 + i];   // 2x b128, broadcast
#pragma unroll
            for (int j = 0; j < 4; j++) wr[j] = wt[k][cg * 4 + j];   // 1x b128, 16B stride
#pragma unroll
            for (int i = 0; i < 8; i++)
#pragma unroll
                for (int j = 0; j < 4; j++) acc[i][j] = fmaf(xr[i], wr[j], acc[i][j]);
        }
        __syncthreads();
    }

    float4 bb = *(const float4*)&b_dt[d0 + cg * 4];
#pragma unroll
    for (int i = 0; i < 8; i++) {
        int row = row0 + rg * 8 + i;
        float4 o;
        o.x = softplusf(acc[i][0] + bb.x);
        o.y = softplusf(acc[i][1] + bb.y);
        o.z = softplusf(acc[i][2] + bb.z);
        o.w = softplusf(acc[i][3] + bb.w);
        *(float4*)&delta[(long)row * DI + d0 + cg * 4] = o;
    }
}

// ===== S1: chunk-local carries; B staged in LDS (broadcast reads) =====
__global__ __launch_bounds__(256) void scan_carry(const float* __restrict__ x,
                                                  const float* __restrict__ delta,
                                                  const float* __restrict__ xdbl,
                                                  const float* __restrict__ A_log,
                                                  float* __restrict__ hloc,
                                                  float* __restrict__ dsumb) {
    __shared__ float bs[CL * NST];   // 2 KB
    const int tid = threadIdx.x;
    const int d = blockIdx.x * 256 + tid;
    const int c = blockIdx.y;
    const int b = blockIdx.z;
    const int row0 = b * L_SEQ + c * CL;

    for (int i = tid; i < CL * NST / 4; i += 256) {   // 128 float4
        int row = i >> 2, q = i & 3;
        ((float4*)bs)[i] = *(const float4*)&xdbl[(long)(row0 + row) * E_DIM + 64 + q * 4];
    }
    __syncthreads();

    float A[16];
#pragma unroll
    for (int q = 0; q < 4; q++) {
        float4 v = *(const float4*)&A_log[(long)d * NST + q * 4];
        A[q * 4 + 0] = -__expf(v.x);
        A[q * 4 + 1] = -__expf(v.y);
        A[q * 4 + 2] = -__expf(v.z);
        A[q * 4 + 3] = -__expf(v.w);
    }
    float h[16];
#pragma unroll
    for (int n = 0; n < 16; n++) h[n] = 0.f;
    float dsum = 0.f;

    long idx = (long)row0 * DI + d;
    float dn = delta[idx], xn = x[idx];
    for (int ll = 0; ll < CL; ll++) {
        float dc = dn, xc = xn;
        if (ll + 1 < CL) { dn = delta[idx + DI]; xn = x[idx + DI]; }
        float du = dc * xc;
        float bl[16];
#pragma unroll
        for (int q = 0; q < 4; q++) {
            float4 v = *(const float4*)&bs[ll * NST + q * 4];   // broadcast
            bl[q * 4 + 0] = v.x; bl[q * 4 + 1] = v.y; bl[q * 4 + 2] = v.z; bl[q * 4 + 3] = v.w;
        }
#pragma unroll
        for (int n = 0; n < 16; n++)
            h[n] = fmaf(__expf(dc * A[n]), h[n], du * bl[n]);
        dsum += dc;
        idx += DI;
    }

    const long cb = ((long)(b * NCH + c) * DI + d);
#pragma unroll
    for (int q = 0; q < 4; q++)
        *(float4*)&hloc[cb * 16 + q * 4] =
            make_float4(h[q * 4], h[q * 4 + 1], h[q * 4 + 2], h[q * 4 + 3]);
    dsumb[cb] = dsum;
}

// ===== S2: prefix over chunks; hloc becomes chunk-entry state =====
__global__ __launch_bounds__(256) void scan_prefix(const float* __restrict__ A_log,
                                                   float* __restrict__ hloc,
                                                   const float* __restrict__ dsumb) {
    const int g = blockIdx.x * 256 + threadIdx.x;   // 65536 threads
    const int n = g & 15;
    const int d = (g >> 4) & (DI - 1);
    const int b = g >> 15;
    const float An = -__expf(A_log[(long)d * NST + n]);
    float hc = 0.f;
    for (int c = 0; c < NCH; c++) {
        const long cb = ((long)(b * NCH + c) * DI + d);
        float hl = hloc[cb * 16 + n];
        float dsv = dsumb[cb];
        hloc[cb * 16 + n] = hc;               // overwrite with entry state
        hc = fmaf(__expf(An * dsv), hc, hl);  // state at end of chunk c
    }
}

// ===== S3: output pass — B/C staged in LDS (broadcast reads) =====
__global__ __launch_bounds__(256) void scan_out(const float* __restrict__ x,
                                                const float* __restrict__ xdbl,
                                                const float* __restrict__ A_log,
                                                const float* __restrict__ Dp,
                                                const float* __restrict__ hloc,
                                                float* __restrict__ out) {
    __shared__ float bs[CL * NST];
    __shared__ float cs[CL * NST];
    const int tid = threadIdx.x;
    const int d = blockIdx.x * 256 + tid;
    const int c = blockIdx.y;
    const int b = blockIdx.z;
    const int row0 = b * L_SEQ + c * CL;

    for (int i = tid; i < CL * NST / 4; i += 256) {   // 128 float4 each
        int row = i >> 2, q = i & 3;
        ((float4*)bs)[i] = *(const float4*)&xdbl[(long)(row0 + row) * E_DIM + 64 + q * 4];
        ((float4*)cs)[i] = *(const float4*)&xdbl[(long)(row0 + row) * E_DIM + 80 + q * 4];
    }
    __syncthreads();

    float A[16];
#pragma unroll
    for (int q = 0; q < 4; q++) {
        float4 v = *(const float4*)&A_log[(long)d * NST + q * 4];
        A[q * 4 + 0] = -__expf(v.x);
        A[q * 4 + 1] = -__expf(v.y);
        A[q * 4 + 2] = -__expf(v.z);
        A[q * 4 + 3] = -__expf(v.w);
    }
    float h[16];
    const long cb = ((long)(b * NCH + c) * DI + d);
#pragma unroll
    for (int q = 0; q < 4; q++) {
        float4 v = *(const float4*)&hloc[cb * 16 + q * 4];
        h[q * 4 + 0] = v.x; h[q * 4 + 1] = v.y; h[q * 4 + 2] = v.z; h[q * 4 + 3] = v.w;
    }
    const float Dd = Dp[d];

    long idx = (long)row0 * DI + d;
    float dn = out[idx], xn = x[idx];   // out currently holds delta
    for (int ll = 0; ll < CL; ll++) {
        float dc = dn, xc = xn;
        if (ll + 1 < CL) { dn = out[idx + DI]; xn = x[idx + DI]; }
        float du = dc * xc;
        float y = 0.f;
#pragma unroll
        for (int q = 0; q < 4; q++) {
            float4 v = *(const float4*)&bs[ll * NST + q * 4];
            float4 w = *(const float4*)&cs[ll * NST + q * 4];
            float e0 = __expf(dc * A[q * 4 + 0]);
            float e1 = __expf(dc * A[q * 4 + 1]);
            float e2 = __expf(dc * A[q * 4 + 2]);
            float e3 = __expf(dc * A[q * 4 + 3]);
            h[q * 4 + 0] = fmaf(e0, h[q * 4 + 0], du * v.x);
            h[q * 4 + 1] = fmaf(e1, h[q * 4 + 1], du * v.y);
            h[q * 4 + 2] = fmaf(e2, h[q * 4 + 2], du * v.z);
            h[q * 4 + 3] = fmaf(e3, h[q * 4 + 3], du * v.w);
            y = fmaf(h[q * 4 + 0], w.x, y);
            y = fmaf(h[q * 4 + 1], w.y, y);
            y = fmaf(h[q * 4 + 2], w.z, y);
            y = fmaf(h[q * 4 + 3], w.w, y);
        }
        out[idx] = fmaf(xc, Dd, y);
        idx += DI;
    }
}

extern "C" void kernel_launch(void* const* d_in, const int* in_sizes, int n_in,
                              void* d_out, int out_size, void* d_ws, size_t ws_size,
                              hipStream_t stream) {
    const float* x    = (const float*)d_in[0];
    const float* Wx   = (const float*)d_in[1];
    const float* Wdt  = (const float*)d_in[2];
    const float* bdt  = (const float*)d_in[3];
    const float* Alog = (const float*)d_in[4];
    const float* Dp   = (const float*)d_in[5];
    float* out = (float*)d_out;
    float* ws = (float*)d_ws;
    float* xdbl  = ws + WS_XDBL;
    float* partb = ws + WS_PART;
    float* hloc  = ws + WS_HLOC;   // overlays partb (disjoint lifetime)
    float* dsumb = ws + WS_DSUM;

    gemm_xproj_part<<<dim3(NROW / 64, SPLITK), 256, 0, stream>>>(x, Wx, partb);
    xproj_reduce<<<dim3(NROW * E_DIM / 4 / 256), 256, 0, stream>>>(partb, xdbl);
    gemm_dt<<<dim3(NROW / 64, DI / 128), 256, 0, stream>>>(xdbl, Wdt, bdt, out);
    scan_carry<<<dim3(DI / 256, NCH, BATCH), 256, 0, stream>>>(x, out, xdbl, Alog, hloc, dsumb);
    scan_prefix<<<dim3(BATCH * DI * NST / 256), 256, 0, stream>>>(Alog, hloc, dsumb);
    scan_out<<<dim3(DI / 256, NCH, BATCH), 256, 0, stream>>>(x, xdbl, Alog, Dp, hloc, out);
}